// Round 12
// baseline (159.460 us; speedup 1.0000x reference)
//
#include <hip/hip_runtime.h>
#include <cstdint>
#include <cstddef>

typedef __bf16 bf16x8 __attribute__((ext_vector_type(8)));
typedef float f32x4 __attribute__((ext_vector_type(4)));
typedef float f32x16 __attribute__((ext_vector_type(16)));
typedef unsigned int u32x2 __attribute__((ext_vector_type(2)));
typedef unsigned int u32x4 __attribute__((ext_vector_type(4)));

#define MFMA16(a, b, c) __builtin_amdgcn_mfma_f32_16x16x32_bf16((a), (b), (c), 0, 0, 0)
#define MFMA32(a, b, c) __builtin_amdgcn_mfma_f32_32x32x16_bf16((a), (b), (c), 0, 0, 0)

// Barrier WITHOUT the vmcnt(0) drain __syncthreads() emits.
#define BAR() asm volatile("s_waitcnt lgkmcnt(0)\n\ts_barrier" ::: "memory")

static constexpr int CD = 128;
static constexpr int NTOK = 65536;
static constexpr float F_SCALE = 0.17677669529663688f;  // 1/sqrt(32)
static constexpr float F_LOG2E = 1.4426950408889634f;
static constexpr int PART = 4224;    // 4096 S + 128 Z floats per k1 block
static constexpr int NPARTS = 128;   // k1 blocks per batch

__device__ __forceinline__ unsigned pk2(float a, float b) {
  unsigned short ua = __builtin_bit_cast(unsigned short, (__bf16)a);
  unsigned short ub = __builtin_bit_cast(unsigned short, (__bf16)b);
  return (unsigned)ua | ((unsigned)ub << 16);
}

__device__ __forceinline__ f32x16 z16() {
  f32x16 v;
#pragma unroll
  for (int i = 0; i < 16; ++i) v[i] = 0.f;
  return v;
}

// ---------- k1 staging ----------
struct Grp { f32x4 M[4]; };

__device__ __forceinline__ Grp load_grp(const float* src, int lane) {
  Grp g;
  const float* p = src + (size_t)((lane >> 4) * 4) * NTOK + (lane & 15) * 4;
#pragma unroll
  for (int v = 0; v < 4; ++v) g.M[v] = *(const f32x4*)(p + (size_t)v * NTOK);
  return g;
}

__device__ __forceinline__ void pack_grp(const Grp& g, char* T2, int cqBase, int lane) {
  int cq = cqBase + (lane >> 4);
  int nq = lane & 15;
#pragma unroll
  for (int j = 0; j < 4; ++j) {
    int n = nq * 4 + j;
    *(u32x2*)(T2 + n * 256 + ((cq * 8) ^ ((((n & 15) ^ (n >> 4))) << 4))) =
        u32x2{pk2(g.M[0][j], g.M[1][j]), pk2(g.M[2][j], g.M[3][j])};
  }
}

// ---------- k3 staging ----------
struct Grp32 { f32x4 M[4]; };

__device__ __forceinline__ Grp32 load_grp32(const float* src, int lane) {
  Grp32 g;
  int q = (lane >> 3) & 7;
  const float* p = src + (size_t)(2 * q) * NTOK + (lane & 7) * 4;
  g.M[0] = *(const f32x4*)p;
  g.M[1] = *(const f32x4*)(p + NTOK);
  g.M[2] = *(const f32x4*)(p + (size_t)16 * NTOK);
  g.M[3] = *(const f32x4*)(p + (size_t)17 * NTOK);
  return g;
}

__device__ __forceinline__ void pack_grp32(const Grp32& g, char* T2, int cpBase, int lane) {
  int q = (lane >> 3) & 7;
  int a = lane & 7;
#pragma unroll
  for (int j = 0; j < 4; ++j) {
    int n = a * 4 + j;
    int sw = (((n & 15) ^ (n >> 4)) << 4);
    *(unsigned*)(T2 + n * 256 + (((cpBase + q) * 4) ^ sw)) = pk2(g.M[0][j], g.M[1][j]);
    *(unsigned*)(T2 + n * 256 + (((cpBase + 8 + q) * 4) ^ sw)) = pk2(g.M[2][j], g.M[3][j]);
  }
}

// ---------------- kernel 1: context -> S,Z partials (unchanged R9) ----------------
__global__ __launch_bounds__(256) __attribute__((amdgpu_waves_per_eu(2)))
void k1_ctx(const float* __restrict__ ctx_in, const float* __restrict__ Wk,
            const float* __restrict__ Wv, float* __restrict__ S_part) {
  __shared__ char smem[32 * 1024];  // T2 dbuf 2 x 16KB
  const int tid = threadIdx.x;
  const int lane = tid & 63;
  const int w = tid >> 6;
  const int l31 = lane & 31;
  const int l2 = lane >> 5;
  const int b = blockIdx.x >> 7;
  const int cb = blockIdx.x & 127;

  bf16x8 WfK[8], WfV[8];
#pragma unroll
  for (int ks = 0; ks < 8; ++ks) {
    const float* pK = Wk + (size_t)(w * 32 + l31) * CD + ks * 16 + l2 * 8;
    const float* pV = Wv + (size_t)(w * 32 + l31) * CD + ks * 16 + l2 * 8;
#pragma unroll
    for (int e = 0; e < 8; ++e) {
      WfK[ks][e] = (__bf16)(pK[e] * F_LOG2E);
      WfV[ks][e] = (__bf16)pV[e];
    }
  }

  f32x16 Sacc = z16();
  float zacc = 0.f;

  const float* srcA = ctx_in + (size_t)b * CD * NTOK + (size_t)(w * 32) * NTOK + cb * 512;
  const float* srcB = srcA + (size_t)16 * NTOK;

  Grp fa = load_grp(srcA, lane), fb = load_grp(srcB, lane);
#pragma unroll
  for (int s = 0; s < 8; ++s) {
    char* T2 = smem + (s & 1) * 16384;
    pack_grp(fa, T2, w * 8, lane);
    pack_grp(fb, T2, w * 8 + 4, lane);
    if (s < 7) {
      fa = load_grp(srcA + (s + 1) * 64, lane);
      fb = load_grp(srcB + (s + 1) * 64, lane);
    }
    BAR();

    unsigned pe[2][4][2], pv[2][4][2];
#pragma unroll
    for (int t = 0; t < 2; ++t) {
      f32x16 aK = z16(), aV = z16();
#pragma unroll
      for (int ks = 0; ks < 8; ++ks) {
        bf16x8 At = *(const bf16x8*)(
            T2 + (t * 32 + l31) * 256 +
            ((ks * 32 + l2 * 16) ^ (((l31 & 15) ^ (2 * t + (l31 >> 4))) << 4)));
        aK = MFMA32(At, WfK[ks], aK);
        aV = MFMA32(At, WfV[ks], aV);
      }
#pragma unroll
      for (int q = 0; q < 4; ++q) {
        float e0 = __builtin_exp2f(aK[4 * q + 0]);
        float e1 = __builtin_exp2f(aK[4 * q + 1]);
        float e2 = __builtin_exp2f(aK[4 * q + 2]);
        float e3 = __builtin_exp2f(aK[4 * q + 3]);
        zacc += (e0 + e1) + (e2 + e3);
        pe[t][q][0] = pk2(e0, e1);
        pe[t][q][1] = pk2(e2, e3);
        pv[t][q][0] = pk2(aV[4 * q + 0], aV[4 * q + 1]);
        pv[t][q][1] = pk2(aV[4 * q + 2], aV[4 * q + 3]);
      }
    }

#pragma unroll
    for (int nw = 0; nw < 4; ++nw) {
      const int t = nw >> 1, w2 = nw & 1;
      unsigned ea0 = pe[t][2 * w2][0], eb0 = pe[t][2 * w2 + 1][0];
      unsigned ea1 = pe[t][2 * w2][1], eb1 = pe[t][2 * w2 + 1][1];
      asm("v_permlane32_swap_b32 %0, %1" : "+v"(ea0), "+v"(eb0));
      asm("v_permlane32_swap_b32 %0, %1" : "+v"(ea1), "+v"(eb1));
      unsigned va0 = pv[t][2 * w2][0], vb0 = pv[t][2 * w2 + 1][0];
      unsigned va1 = pv[t][2 * w2][1], vb1 = pv[t][2 * w2 + 1][1];
      asm("v_permlane32_swap_b32 %0, %1" : "+v"(va0), "+v"(vb0));
      asm("v_permlane32_swap_b32 %0, %1" : "+v"(va1), "+v"(vb1));
      bf16x8 Ea = __builtin_bit_cast(bf16x8, u32x4{ea0, ea1, eb0, eb1});
      bf16x8 Vb = __builtin_bit_cast(bf16x8, u32x4{va0, va1, vb0, vb1});
      Sacc = MFMA32(Ea, Vb, Sacc);
    }
  }

  float* outp = S_part + (size_t)blockIdx.x * PART;
#pragma unroll
  for (int q = 0; q < 4; ++q) {
    f32x4 v{Sacc[4 * q + 0], Sacc[4 * q + 1], Sacc[4 * q + 2], Sacc[4 * q + 3]};
    *(f32x4*)(outp + w * 1024 + lane * 16 + q * 4) = v;
  }
  zacc += __shfl_xor(zacc, 32, 64);
  if (l2 == 0) outp[4096 + w * 32 + l31] = zacc;
}

// ---------------- kernel 2a: reduce partials (unchanged) ----------------
__global__ void k2a_reduce(const float* __restrict__ S_part, float* __restrict__ S_red,
                           float* __restrict__ Z_red) {
  int bid = blockIdx.x;
  int b = bid / 33, bs = bid % 33;
  int tid = threadIdx.x;
  __shared__ float red[256];
  int e_loc = tid & 127, half = tid >> 7;
  const float* base =
      S_part + (size_t)b * NPARTS * PART + (bs < 32 ? bs * 128 + e_loc : 4096 + e_loc);
  float sum = 0.f;
  int h = NPARTS >> 1;
  for (int p = half * h; p < half * h + h; ++p) sum += base[(size_t)p * PART];
  red[tid] = sum;
  __syncthreads();
  if (tid < 128) {
    float v = red[tid] + red[tid + 128];
    if (bs < 32)
      S_red[b * 4096 + bs * 128 + tid] = v;
    else
      Z_red[b * 128 + tid] = v;
  }
}

// ---------------- kernel 2b (unchanged) ----------------
__global__ void k2b_weff(const float* __restrict__ S_red, const float* __restrict__ Z_red,
                         const float* __restrict__ Wq, const float* __restrict__ Wo,
                         float* __restrict__ W_eff) {
  int b = blockIdx.x >> 3, og = blockIdx.x & 7;
  int tid = threadIdx.x;
  __shared__ float ctx_lds[4096];  // [h][d][e]
  __shared__ float T_lds[16 * 128];
  for (int i = tid * 16; i < tid * 16 + 16; ++i) {
    int h = i >> 10, d = (i >> 5) & 31, e = i & 31;
    int fl = h * 1024 + ((e + ((d >> 2) & 1) * 32) << 4) + (d & 3) + ((d >> 3) << 2);
    ctx_lds[i] = S_red[b * 4096 + fl] / Z_red[b * 128 + h * 32 + d];
  }
  __syncthreads();
  {
    int o_loc = tid >> 4, hd0 = (tid & 15) * 8;
    int o = og * 16 + o_loc;
    for (int j = 0; j < 8; ++j) {
      int hd = hd0 + j, h = hd >> 5, d = hd & 31;
      const float* wo = Wo + o * 128 + h * 32;
      const float* cx = ctx_lds + h * 1024 + d * 32;
      float acc = 0.f;
      for (int e = 0; e < 32; ++e) acc += wo[e] * cx[e];
      T_lds[o_loc * 128 + hd] = acc;
    }
  }
  __syncthreads();
  {
    int o_loc = tid >> 4, c0 = (tid & 15) * 8;
    float acc[8] = {};
    const float* Trow = T_lds + o_loc * 128;
    for (int hd = 0; hd < 128; ++hd) {
      float tv = Trow[hd];
      const float* wq = Wq + hd * 128 + c0;
#pragma unroll
      for (int j = 0; j < 8; ++j) acc[j] += tv * wq[j];
    }
    float* op = W_eff + b * 16384 + (og * 16 + o_loc) * 128 + c0;
#pragma unroll
    for (int j = 0; j < 8; ++j) op[j] = F_SCALE * acc[j];
  }
}

// ---------------- kernel 3: out = W_eff[b] @ x[b] + bo ----------------
// R11 structure; ONE change: output stores are NON-TEMPORAL so the 134MB
// out-stream doesn't evict x/context from L3 (inputs ~268MB vs L3 256MB).
__global__ __launch_bounds__(256, 4) void k3_out(const float* __restrict__ x,
                                                 const float* __restrict__ W_eff,
                                                 const float* __restrict__ bo,
                                                 float* __restrict__ out) {
  __shared__ char smem[16 * 1024];  // T2 dbuf 2 x 8KB
  const int tid = threadIdx.x;
  const int lane = tid & 63;
  const int w = tid >> 6;
  const int l15 = lane & 15;
  const int lg = lane >> 4;
  const int b = blockIdx.x >> 8;
  const int cb = blockIdx.x & 255;

  bf16x8 Wf[2][4];
#pragma unroll
  for (int m = 0; m < 2; ++m) {
    int o = w * 32 + m * 16 + l15;
#pragma unroll
    for (int ks = 0; ks < 4; ++ks) {
      const float* p = W_eff + b * 16384 + o * 128 + ks * 32 + lg * 8;
#pragma unroll
      for (int e = 0; e < 8; ++e) Wf[m][ks][e] = (__bf16)p[e];
    }
  }
  float bof[2] = {bo[w * 32 + l15], bo[w * 32 + 16 + l15]};

  const float* src = x + (size_t)b * CD * NTOK + (size_t)(w * 32) * NTOK + cb * 256;
  float* dst = out + (size_t)b * CD * NTOK + cb * 256;

  Grp32 f0 = load_grp32(src, lane);
  Grp32 f1 = load_grp32(src + 32, lane);
  Grp32 f2 = load_grp32(src + 64, lane);

#pragma unroll
  for (int s = 0; s < 8; ++s) {
    char* T2 = smem + (s & 1) * 8192;
    if ((s % 3) == 0) {
      pack_grp32(f0, T2, w * 16, lane);
      if (s + 3 < 8) f0 = load_grp32(src + (s + 3) * 32, lane);
    } else if ((s % 3) == 1) {
      pack_grp32(f1, T2, w * 16, lane);
      if (s + 3 < 8) f1 = load_grp32(src + (s + 3) * 32, lane);
    } else {
      pack_grp32(f2, T2, w * 16, lane);
      if (s + 3 < 8) f2 = load_grp32(src + (s + 3) * 32, lane);
    }
    BAR();

#pragma unroll
    for (int t = 0; t < 2; ++t) {
      f32x4 acc[2];
      acc[0] = f32x4{0.f, 0.f, 0.f, 0.f};
      acc[1] = f32x4{0.f, 0.f, 0.f, 0.f};
#pragma unroll
      for (int ks = 0; ks < 4; ++ks) {
        bf16x8 At = *(const bf16x8*)(T2 + (t * 16 + l15) * 256 +
                                     ((ks * 64 + lg * 16) ^ ((l15 ^ t) << 4)));
#pragma unroll
        for (int m = 0; m < 2; ++m) acc[m] = MFMA16(At, Wf[m][ks], acc[m]);
      }
#pragma unroll
      for (int m = 0; m < 2; ++m) {
        int o = w * 32 + m * 16 + l15;
        f32x4 v = acc[m];
        v[0] += bof[m]; v[1] += bof[m]; v[2] += bof[m]; v[3] += bof[m];
        __builtin_nontemporal_store(
            v, (f32x4*)(dst + (size_t)o * NTOK + s * 32 + t * 16 + lg * 4));
      }
    }
  }
}

extern "C" void kernel_launch(void* const* d_in, const int* in_sizes, int n_in,
                              void* d_out, int out_size, void* d_ws, size_t ws_size,
                              hipStream_t stream) {
  const float* x = (const float*)d_in[0];
  const float* ctxg = (const float*)d_in[1];
  const float* Wq = (const float*)d_in[2];
  const float* Wk = (const float*)d_in[3];
  const float* Wv = (const float*)d_in[4];
  const float* Wo = (const float*)d_in[5];
  const float* bo = (const float*)d_in[6];
  float* out = (float*)d_out;

  float* ws = (float*)d_ws;
  float* S_part = ws;                         // 512 * 4224 floats
  float* S_red = ws + (size_t)512 * PART;     // 16384
  float* Z_red = S_red + 16384;               // 512
  float* W_eff = Z_red + 512;                 // 65536

  k1_ctx<<<dim3(512), dim3(256), 0, stream>>>(ctxg, Wk, Wv, S_part);
  k2a_reduce<<<dim3(132), dim3(256), 0, stream>>>(S_part, S_red, Z_red);
  k2b_weff<<<dim3(32), dim3(256), 0, stream>>>(S_red, Z_red, Wq, Wo, W_eff);
  k3_out<<<dim3(1024), dim3(256), 0, stream>>>(x, W_eff, bo, out);
}

// Round 13
// 154.346 us; speedup vs baseline: 1.0331x; 1.0331x over previous
//
#include <hip/hip_runtime.h>
#include <cstdint>
#include <cstddef>

typedef __bf16 bf16x8 __attribute__((ext_vector_type(8)));
typedef float f32x4 __attribute__((ext_vector_type(4)));
typedef float f32x16 __attribute__((ext_vector_type(16)));
typedef unsigned int u32x2 __attribute__((ext_vector_type(2)));
typedef unsigned int u32x4 __attribute__((ext_vector_type(4)));

#define MFMA16(a, b, c) __builtin_amdgcn_mfma_f32_16x16x32_bf16((a), (b), (c), 0, 0, 0)
#define MFMA32(a, b, c) __builtin_amdgcn_mfma_f32_32x32x16_bf16((a), (b), (c), 0, 0, 0)

// Barrier WITHOUT the vmcnt(0) drain __syncthreads() emits.
#define BAR() asm volatile("s_waitcnt lgkmcnt(0)\n\ts_barrier" ::: "memory")

static constexpr int CD = 128;
static constexpr int NTOK = 65536;
static constexpr float F_SCALE = 0.17677669529663688f;  // 1/sqrt(32)
static constexpr float F_LOG2E = 1.4426950408889634f;
static constexpr int PART = 4224;    // 4096 S + 128 Z floats per k1 block
static constexpr int NPARTS = 128;   // k1 blocks per batch

__device__ __forceinline__ unsigned pk2(float a, float b) {
  unsigned short ua = __builtin_bit_cast(unsigned short, (__bf16)a);
  unsigned short ub = __builtin_bit_cast(unsigned short, (__bf16)b);
  return (unsigned)ua | ((unsigned)ub << 16);
}

__device__ __forceinline__ f32x16 z16() {
  f32x16 v;
#pragma unroll
  for (int i = 0; i < 16; ++i) v[i] = 0.f;
  return v;
}

// ---------- k1 staging ----------
struct Grp { f32x4 M[4]; };

__device__ __forceinline__ Grp load_grp(const float* src, int lane) {
  Grp g;
  const float* p = src + (size_t)((lane >> 4) * 4) * NTOK + (lane & 15) * 4;
#pragma unroll
  for (int v = 0; v < 4; ++v) g.M[v] = *(const f32x4*)(p + (size_t)v * NTOK);
  return g;
}

__device__ __forceinline__ void pack_grp(const Grp& g, char* T2, int cqBase, int lane) {
  int cq = cqBase + (lane >> 4);
  int nq = lane & 15;
#pragma unroll
  for (int j = 0; j < 4; ++j) {
    int n = nq * 4 + j;
    *(u32x2*)(T2 + n * 256 + ((cq * 8) ^ ((((n & 15) ^ (n >> 4))) << 4))) =
        u32x2{pk2(g.M[0][j], g.M[1][j]), pk2(g.M[2][j], g.M[3][j])};
  }
}

// ---------- k3 staging ----------
struct Grp32 { f32x4 M[4]; };

__device__ __forceinline__ Grp32 load_grp32(const float* src, int lane) {
  Grp32 g;
  int q = (lane >> 3) & 7;
  const float* p = src + (size_t)(2 * q) * NTOK + (lane & 7) * 4;
  g.M[0] = *(const f32x4*)p;
  g.M[1] = *(const f32x4*)(p + NTOK);
  g.M[2] = *(const f32x4*)(p + (size_t)16 * NTOK);
  g.M[3] = *(const f32x4*)(p + (size_t)17 * NTOK);
  return g;
}

__device__ __forceinline__ void pack_grp32(const Grp32& g, char* T2, int cpBase, int lane) {
  int q = (lane >> 3) & 7;
  int a = lane & 7;
#pragma unroll
  for (int j = 0; j < 4; ++j) {
    int n = a * 4 + j;
    int sw = (((n & 15) ^ (n >> 4)) << 4);
    *(unsigned*)(T2 + n * 256 + (((cpBase + q) * 4) ^ sw)) = pk2(g.M[0][j], g.M[1][j]);
    *(unsigned*)(T2 + n * 256 + (((cpBase + 8 + q) * 4) ^ sw)) = pk2(g.M[2][j], g.M[3][j]);
  }
}

// ---------------- kernel 1: context -> S,Z partials (unchanged R11) ----------------
__global__ __launch_bounds__(256) __attribute__((amdgpu_waves_per_eu(2)))
void k1_ctx(const float* __restrict__ ctx_in, const float* __restrict__ Wk,
            const float* __restrict__ Wv, float* __restrict__ S_part) {
  __shared__ char smem[32 * 1024];  // T2 dbuf 2 x 16KB
  const int tid = threadIdx.x;
  const int lane = tid & 63;
  const int w = tid >> 6;
  const int l31 = lane & 31;
  const int l2 = lane >> 5;
  const int b = blockIdx.x >> 7;
  const int cb = blockIdx.x & 127;

  bf16x8 WfK[8], WfV[8];
#pragma unroll
  for (int ks = 0; ks < 8; ++ks) {
    const float* pK = Wk + (size_t)(w * 32 + l31) * CD + ks * 16 + l2 * 8;
    const float* pV = Wv + (size_t)(w * 32 + l31) * CD + ks * 16 + l2 * 8;
#pragma unroll
    for (int e = 0; e < 8; ++e) {
      WfK[ks][e] = (__bf16)(pK[e] * F_LOG2E);
      WfV[ks][e] = (__bf16)pV[e];
    }
  }

  f32x16 Sacc = z16();
  float zacc = 0.f;

  const float* srcA = ctx_in + (size_t)b * CD * NTOK + (size_t)(w * 32) * NTOK + cb * 512;
  const float* srcB = srcA + (size_t)16 * NTOK;

  Grp fa = load_grp(srcA, lane), fb = load_grp(srcB, lane);
#pragma unroll
  for (int s = 0; s < 8; ++s) {
    char* T2 = smem + (s & 1) * 16384;
    pack_grp(fa, T2, w * 8, lane);
    pack_grp(fb, T2, w * 8 + 4, lane);
    if (s < 7) {
      fa = load_grp(srcA + (s + 1) * 64, lane);
      fb = load_grp(srcB + (s + 1) * 64, lane);
    }
    BAR();

    unsigned pe[2][4][2], pv[2][4][2];
#pragma unroll
    for (int t = 0; t < 2; ++t) {
      f32x16 aK = z16(), aV = z16();
#pragma unroll
      for (int ks = 0; ks < 8; ++ks) {
        bf16x8 At = *(const bf16x8*)(
            T2 + (t * 32 + l31) * 256 +
            ((ks * 32 + l2 * 16) ^ (((l31 & 15) ^ (2 * t + (l31 >> 4))) << 4)));
        aK = MFMA32(At, WfK[ks], aK);
        aV = MFMA32(At, WfV[ks], aV);
      }
#pragma unroll
      for (int q = 0; q < 4; ++q) {
        float e0 = __builtin_exp2f(aK[4 * q + 0]);
        float e1 = __builtin_exp2f(aK[4 * q + 1]);
        float e2 = __builtin_exp2f(aK[4 * q + 2]);
        float e3 = __builtin_exp2f(aK[4 * q + 3]);
        zacc += (e0 + e1) + (e2 + e3);
        pe[t][q][0] = pk2(e0, e1);
        pe[t][q][1] = pk2(e2, e3);
        pv[t][q][0] = pk2(aV[4 * q + 0], aV[4 * q + 1]);
        pv[t][q][1] = pk2(aV[4 * q + 2], aV[4 * q + 3]);
      }
    }

#pragma unroll
    for (int nw = 0; nw < 4; ++nw) {
      const int t = nw >> 1, w2 = nw & 1;
      unsigned ea0 = pe[t][2 * w2][0], eb0 = pe[t][2 * w2 + 1][0];
      unsigned ea1 = pe[t][2 * w2][1], eb1 = pe[t][2 * w2 + 1][1];
      asm("v_permlane32_swap_b32 %0, %1" : "+v"(ea0), "+v"(eb0));
      asm("v_permlane32_swap_b32 %0, %1" : "+v"(ea1), "+v"(eb1));
      unsigned va0 = pv[t][2 * w2][0], vb0 = pv[t][2 * w2 + 1][0];
      unsigned va1 = pv[t][2 * w2][1], vb1 = pv[t][2 * w2 + 1][1];
      asm("v_permlane32_swap_b32 %0, %1" : "+v"(va0), "+v"(vb0));
      asm("v_permlane32_swap_b32 %0, %1" : "+v"(va1), "+v"(vb1));
      bf16x8 Ea = __builtin_bit_cast(bf16x8, u32x4{ea0, ea1, eb0, eb1});
      bf16x8 Vb = __builtin_bit_cast(bf16x8, u32x4{va0, va1, vb0, vb1});
      Sacc = MFMA32(Ea, Vb, Sacc);
    }
  }

  float* outp = S_part + (size_t)blockIdx.x * PART;
#pragma unroll
  for (int q = 0; q < 4; ++q) {
    f32x4 v{Sacc[4 * q + 0], Sacc[4 * q + 1], Sacc[4 * q + 2], Sacc[4 * q + 3]};
    *(f32x4*)(outp + w * 1024 + lane * 16 + q * 4) = v;
  }
  zacc += __shfl_xor(zacc, 32, 64);
  if (l2 == 0) outp[4096 + w * 32 + l31] = zacc;
}

// ---------------- kernel 2a: reduce partials (unchanged) ----------------
__global__ void k2a_reduce(const float* __restrict__ S_part, float* __restrict__ S_red,
                           float* __restrict__ Z_red) {
  int bid = blockIdx.x;
  int b = bid / 33, bs = bid % 33;
  int tid = threadIdx.x;
  __shared__ float red[256];
  int e_loc = tid & 127, half = tid >> 7;
  const float* base =
      S_part + (size_t)b * NPARTS * PART + (bs < 32 ? bs * 128 + e_loc : 4096 + e_loc);
  float sum = 0.f;
  int h = NPARTS >> 1;
  for (int p = half * h; p < half * h + h; ++p) sum += base[(size_t)p * PART];
  red[tid] = sum;
  __syncthreads();
  if (tid < 128) {
    float v = red[tid] + red[tid + 128];
    if (bs < 32)
      S_red[b * 4096 + bs * 128 + tid] = v;
    else
      Z_red[b * 128 + tid] = v;
  }
}

// ---------------- kernel 2b (unchanged) ----------------
__global__ void k2b_weff(const float* __restrict__ S_red, const float* __restrict__ Z_red,
                         const float* __restrict__ Wq, const float* __restrict__ Wo,
                         float* __restrict__ W_eff) {
  int b = blockIdx.x >> 3, og = blockIdx.x & 7;
  int tid = threadIdx.x;
  __shared__ float ctx_lds[4096];  // [h][d][e]
  __shared__ float T_lds[16 * 128];
  for (int i = tid * 16; i < tid * 16 + 16; ++i) {
    int h = i >> 10, d = (i >> 5) & 31, e = i & 31;
    int fl = h * 1024 + ((e + ((d >> 2) & 1) * 32) << 4) + (d & 3) + ((d >> 3) << 2);
    ctx_lds[i] = S_red[b * 4096 + fl] / Z_red[b * 128 + h * 32 + d];
  }
  __syncthreads();
  {
    int o_loc = tid >> 4, hd0 = (tid & 15) * 8;
    int o = og * 16 + o_loc;
    for (int j = 0; j < 8; ++j) {
      int hd = hd0 + j, h = hd >> 5, d = hd & 31;
      const float* wo = Wo + o * 128 + h * 32;
      const float* cx = ctx_lds + h * 1024 + d * 32;
      float acc = 0.f;
      for (int e = 0; e < 32; ++e) acc += wo[e] * cx[e];
      T_lds[o_loc * 128 + hd] = acc;
    }
  }
  __syncthreads();
  {
    int o_loc = tid >> 4, c0 = (tid & 15) * 8;
    float acc[8] = {};
    const float* Trow = T_lds + o_loc * 128;
    for (int hd = 0; hd < 128; ++hd) {
      float tv = Trow[hd];
      const float* wq = Wq + hd * 128 + c0;
#pragma unroll
      for (int j = 0; j < 8; ++j) acc[j] += tv * wq[j];
    }
    float* op = W_eff + b * 16384 + (og * 16 + o_loc) * 128 + c0;
#pragma unroll
    for (int j = 0; j < 8; ++j) op[j] = F_SCALE * acc[j];
  }
}

// ---------------- kernel 3: out = W_eff[b] @ x[b] + bo (acc-then-burst-store) ----------------
// grid 1024 = 4 b x 256 chunks of 256 n (8 strips of 32 n). READ PHASE: all 8
// strips load+transpose+MFMA, accumulating into 128 statically-indexed VGPRs
// (no stores issued). STORE PHASE: each o-row's full 1KB chunk written by 16
// back-to-back dwordx4 instrs. Separates the R and W streams in time per
// block and gives DRAM long per-row write bursts.
__global__ __launch_bounds__(256, 2) void k3_out(const float* __restrict__ x,
                                                 const float* __restrict__ W_eff,
                                                 const float* __restrict__ bo,
                                                 float* __restrict__ out) {
  __shared__ char smem[16 * 1024];  // T2 dbuf 2 x 8KB
  const int tid = threadIdx.x;
  const int lane = tid & 63;
  const int w = tid >> 6;
  const int l15 = lane & 15;
  const int lg = lane >> 4;
  const int b = blockIdx.x >> 8;
  const int cb = blockIdx.x & 255;

  bf16x8 Wf[2][4];
#pragma unroll
  for (int m = 0; m < 2; ++m) {
    int o = w * 32 + m * 16 + l15;
#pragma unroll
    for (int ks = 0; ks < 4; ++ks) {
      const float* p = W_eff + b * 16384 + o * 128 + ks * 32 + lg * 8;
#pragma unroll
      for (int e = 0; e < 8; ++e) Wf[m][ks][e] = (__bf16)p[e];
    }
  }
  float bof[2] = {bo[w * 32 + l15], bo[w * 32 + 16 + l15]};

  const float* src = x + (size_t)b * CD * NTOK + (size_t)(w * 32) * NTOK + cb * 256;
  float* dst = out + (size_t)b * CD * NTOK + cb * 256;

  Grp32 f0 = load_grp32(src, lane);
  Grp32 f1 = load_grp32(src + 32, lane);
  Grp32 f2 = load_grp32(src + 64, lane);

  f32x4 acc[8][2][2];  // [strip][t][m] -- all indices compile-time (rule #20)
#pragma unroll
  for (int s = 0; s < 8; ++s)
#pragma unroll
    for (int t = 0; t < 2; ++t)
#pragma unroll
      for (int m = 0; m < 2; ++m) acc[s][t][m] = f32x4{0.f, 0.f, 0.f, 0.f};

  // -------- READ PHASE: 8 strips, no global stores --------
#pragma unroll
  for (int s = 0; s < 8; ++s) {
    char* T2 = smem + (s & 1) * 8192;
    if ((s % 3) == 0) {
      pack_grp32(f0, T2, w * 16, lane);
      if (s + 3 < 8) f0 = load_grp32(src + (s + 3) * 32, lane);
    } else if ((s % 3) == 1) {
      pack_grp32(f1, T2, w * 16, lane);
      if (s + 3 < 8) f1 = load_grp32(src + (s + 3) * 32, lane);
    } else {
      pack_grp32(f2, T2, w * 16, lane);
      if (s + 3 < 8) f2 = load_grp32(src + (s + 3) * 32, lane);
    }
    BAR();

#pragma unroll
    for (int t = 0; t < 2; ++t) {
#pragma unroll
      for (int ks = 0; ks < 4; ++ks) {
        bf16x8 At = *(const bf16x8*)(T2 + (t * 16 + l15) * 256 +
                                     ((ks * 64 + lg * 16) ^ ((l15 ^ t) << 4)));
#pragma unroll
        for (int m = 0; m < 2; ++m) acc[s][t][m] = MFMA16(At, Wf[m][ks], acc[s][t][m]);
      }
    }
  }

  // -------- STORE PHASE: per o-row, 16 back-to-back stores cover 1KB --------
#pragma unroll
  for (int m = 0; m < 2; ++m) {
    int o = w * 32 + m * 16 + l15;
    float bb = bof[m];
    float* rowp = dst + (size_t)o * NTOK;
#pragma unroll
    for (int s = 0; s < 8; ++s)
#pragma unroll
      for (int t = 0; t < 2; ++t) {
        f32x4 v = acc[s][t][m];
        v[0] += bb; v[1] += bb; v[2] += bb; v[3] += bb;
        *(f32x4*)(rowp + s * 32 + t * 16 + lg * 4) = v;
      }
  }
}

extern "C" void kernel_launch(void* const* d_in, const int* in_sizes, int n_in,
                              void* d_out, int out_size, void* d_ws, size_t ws_size,
                              hipStream_t stream) {
  const float* x = (const float*)d_in[0];
  const float* ctxg = (const float*)d_in[1];
  const float* Wq = (const float*)d_in[2];
  const float* Wk = (const float*)d_in[3];
  const float* Wv = (const float*)d_in[4];
  const float* Wo = (const float*)d_in[5];
  const float* bo = (const float*)d_in[6];
  float* out = (float*)d_out;

  float* ws = (float*)d_ws;
  float* S_part = ws;                         // 512 * 4224 floats
  float* S_red = ws + (size_t)512 * PART;     // 16384
  float* Z_red = S_red + 16384;               // 512
  float* W_eff = Z_red + 512;                 // 65536

  k1_ctx<<<dim3(512), dim3(256), 0, stream>>>(ctxg, Wk, Wv, S_part);
  k2a_reduce<<<dim3(132), dim3(256), 0, stream>>>(S_part, S_red, Z_red);
  k2b_weff<<<dim3(32), dim3(256), 0, stream>>>(S_red, Z_red, Wq, Wo, W_eff);
  k3_out<<<dim3(1024), dim3(256), 0, stream>>>(x, W_eff, bo, out);
}